// Round 16
// baseline (326.745 us; speedup 1.0000x reference)
//
#include <hip/hip_runtime.h>
#include <hip/hip_bf16.h>
#include <cstdint>
#include <cstddef>

#define N_NODES 204800
#define N_EDGES 3276800
#define NB 2048
#define NR 100
#define NC 64
#define NH 256
#define KPAD 192          // 64 + 100 + bias(1) padded to 192 (6 x K32 steps)
#define NBKT 400          // buckets of 512 dst nodes

typedef __attribute__((ext_vector_type(8))) short short8;
typedef __attribute__((ext_vector_type(4))) float f32x4;
typedef unsigned int uint32;

__device__ __forceinline__ void gload16(const void* g, void* l) {
    __builtin_amdgcn_global_load_lds(
        (const __attribute__((address_space(1))) uint32_t*)(g),
        (__attribute__((address_space(3))) uint32_t*)(l), 16, 0, 0);
}

__device__ __forceinline__ ushort f2bf(float v) {
    __hip_bfloat16 h = __float2bfloat16(v);
    return *reinterpret_cast<ushort*>(&h);
}

__device__ __forceinline__ uint32 pack2bf(float a, float b) {
    return (uint32)f2bf(a) | ((uint32)f2bf(b) << 16);
}

__device__ __forceinline__ float bflo(uint32 v) { return __uint_as_float(v << 16); }
__device__ __forceinline__ float bfhi(uint32 v) { return __uint_as_float(v & 0xFFFF0000u); }

// ---------------- bucket histogram (4096 edges/block) ----------------

__global__ __launch_bounds__(256) void k_bhist(const int* __restrict__ ei,
                                               int* __restrict__ bcnt) {
    __shared__ int h[NBKT];
    int t = threadIdx.x;
    for (int i = t; i < NBKT; i += 256) h[i] = 0;
    __syncthreads();
    #pragma unroll 16
    for (int k = 0; k < 16; ++k) {
        int e = blockIdx.x * 4096 + k * 256 + t;
        atomicAdd(&h[ei[N_EDGES + e] >> 9], 1);
    }
    __syncthreads();
    for (int i = t; i < NBKT; i += 256)
        if (h[i]) atomicAdd(&bcnt[i], h[i]);
}

__global__ void k_bscan(const int* __restrict__ bcnt, int* __restrict__ boffs,
                        int* __restrict__ bcur) {
    __shared__ int tmp[512];
    int t = threadIdx.x;
    int v = (t < NBKT) ? bcnt[t] : 0;
    tmp[t] = v;
    __syncthreads();
    for (int off = 1; off < 512; off <<= 1) {
        int x = 0;
        if (t >= off) x = tmp[t - off];
        __syncthreads();
        tmp[t] += x;
        __syncthreads();
    }
    if (t < NBKT) {
        int o = tmp[t] - v;
        boffs[t] = o;
        bcur[t] = o;
    }
}

// radix partition v2: 4096 edges/block, count -> reserve -> re-read & write.
__global__ __launch_bounds__(256) void k_bscat(const int* __restrict__ ei,
                                               int* __restrict__ bcur,
                                               uint32* __restrict__ part) {
    __shared__ int hist[NBKT];
    __shared__ int curb[NBKT];
    int tid = threadIdx.x;
    for (int i = tid; i < NBKT; i += 256) hist[i] = 0;
    __syncthreads();
    #pragma unroll 16
    for (int k = 0; k < 16; ++k) {
        int e = blockIdx.x * 4096 + k * 256 + tid;
        atomicAdd(&hist[ei[N_EDGES + e] >> 9], 1);
    }
    __syncthreads();
    for (int i = tid; i < NBKT; i += 256) {
        int c = hist[i];
        curb[i] = c ? atomicAdd(&bcur[i], c) : 0;
    }
    __syncthreads();
    #pragma unroll 16
    for (int k = 0; k < 16; ++k) {
        int e = blockIdx.x * 4096 + k * 256 + tid;   // re-read: L2-hot
        int s = ei[e];
        int d = ei[N_EDGES + e];
        int b = d >> 9;
        int p = atomicAdd(&curb[b], 1);
        part[p] = (uint32)s | ((uint32)(d & 511) << 18);
    }
}

// per-bucket counting sort -> CSR ; emits cnt/offs/dinv AND fused ssb
__global__ __launch_bounds__(512) void k_sortb(
    const uint32* __restrict__ part, const int* __restrict__ boffs,
    const int* __restrict__ bcnt, int* __restrict__ csr,
    int* __restrict__ cnt, int* __restrict__ offs, float* __restrict__ dinv,
    const float* __restrict__ state, uint32* __restrict__ ssb32) {
    __shared__ int h[512];
    __shared__ int cur[512];
    __shared__ float sdv[512];
    int b = blockIdx.x, t = threadIdx.x;
    h[t] = 0;
    __syncthreads();
    int base = boffs[b], n = bcnt[b];
    for (int i = t; i < n; i += 512)
        atomicAdd(&h[part[base + i] >> 18], 1);
    __syncthreads();
    int v = h[t];
    int node = b * 512 + t;
    cnt[node] = v;
    float dv = rsqrtf((float)(v + 1));          // +1 self loop
    dinv[node] = dv;
    sdv[t] = dv;
    __syncthreads();
    for (int off = 1; off < 512; off <<= 1) {
        int x = 0;
        if (t >= off) x = h[t - off];
        __syncthreads();
        h[t] += x;
        __syncthreads();
    }
    int excl = h[t] - v;
    offs[node] = base + excl;
    cur[t] = excl;
    __syncthreads();
    for (int i = t; i < n; i += 512) {
        uint32 ew = part[base + i];
        int dl = ew >> 18;
        int pos = atomicAdd(&cur[dl], 1);
        csr[base + pos] = (int)(ew & 0x3FFFF);
    }
    __syncthreads();
    for (int i = t; i < 512 * 32; i += 512) {
        int nl = i >> 5, u = i & 31;
        float d = sdv[nl];
        size_t idx = (size_t)(b * 512 + nl) * 32 + u;
        float2 sv = reinterpret_cast<const float2*>(state)[idx];
        ssb32[idx] = pack2bf(sv.x * d, sv.y * d);
    }
}

// ---------------- pack weights: FRAGMENT-MAJOR ----------------
__global__ void k_packW(const float* __restrict__ W1, const float* __restrict__ W2,
                        const float* __restrict__ Wg, const float* __restrict__ b1,
                        ushort* __restrict__ W1f, ushort* __restrict__ W2f,
                        ushort* __restrict__ Wgt) {
    int t = blockIdx.x * 256 + threadIdx.x;
    if (t < 6 * 4 * 256 * 8) {                      // W1f: 49152 shorts
        int u = t & 7, chunk = t >> 3;
        int tid = chunk & 255, ktI = chunk >> 8;
        int kt = ktI >> 2, i = ktI & 3;
        int l = tid & 63, wp = tid >> 6;
        int k = kt * 32 + (l >> 4) * 8 + u;
        int j = i * 64 + wp * 16 + (l & 15);
        ushort v = 0;
        if (k < NC + NR) v = f2bf(W1[(size_t)k * NH + j]);
        else if (k == NC + NR) v = f2bf(b1[j]);
        W1f[t] = v;
    } else if (t < 49152 + 8 * 4 * 256 * 8) {       // W2f: 65536 shorts
        int t2 = t - 49152;
        int u = t2 & 7, chunk = t2 >> 3;
        int tid = chunk & 255, ktI = chunk >> 8;
        int kt = ktI >> 2, i = ktI & 3;
        int l = tid & 63, wp = tid >> 6;
        int k = kt * 32 + (l >> 4) * 8 + u;
        int j = i * 64 + wp * 16 + (l & 15);
        W2f[t2] = f2bf(W2[(size_t)k * NH + j]);
    } else {
        int t3 = t - 49152 - 65536;
        if (t3 < 64 * 64) {
            int n = t3 >> 6, k = t3 & 63;
            Wgt[t3] = f2bf(Wg[(size_t)k * 64 + n]);
        }
    }
}

// ---------------- FUSED: gather + xW(+relu+residual) + 2-layer MLP + pool ----------------
// 128 rows / block, 512 threads, 8 waves. Phases:
//  (0) issue W1 tile-0 stage; stage Wg^T -> wgs
//  (1) gather (k_gcn inner verbatim; wave w: rows w*16 + rr*2 + half, rr<8) -> av LDS
//  (2) xW via swapped-operand MFMA (lane ends holding x[row=s][j]) + bg + relu
//      + state residual -> xs LDS (bf16)
//  (3) v4b MLP phases 1-2 + epilogue (xf0/xf1 read from xs instead of global)
__global__ __launch_bounds__(512, 4) void k_mlpf(
    const uint32* __restrict__ ssb32, const float* __restrict__ state,
    const int* __restrict__ csr, const int* __restrict__ offs,
    const int* __restrict__ cnt, const float* __restrict__ dinv,
    const ushort* __restrict__ Wgt, const float* __restrict__ bg,
    const float* __restrict__ action,
    const ushort* __restrict__ W1f, const ushort* __restrict__ W2f,
    const float* __restrict__ b2, const float* __restrict__ W3,
    float* __restrict__ out) {
    __shared__ __align__(16) ushort Bs[2][256 * 32];   // 32 KB
    __shared__ __align__(16) uint32 av[128 * 36];      // 18432 B (pitch 144B, 16B-mult)
    __shared__ __align__(16) ushort wgs[64 * 72];      //  9216 B
    __shared__ __align__(16) uint32 xs[128 * 36];      // 18432 B
    int tid = threadIdx.x;
    int w = tid >> 6, lane = tid & 63;
    int s = lane & 15, g = lane >> 4;
    int m0 = blockIdx.x * 128;
    int myrow = m0 + w * 16 + s;
    int gb = myrow / 100, grr = myrow - gb * 100;
    const float* abp = action + (size_t)gb * 10000 + (size_t)grr * 100;

    // (0a) issue W1 tile-0 stage early (completes under the gather)
    #pragma unroll
    for (int tc = 0; tc < 2; ++tc)
        gload16(W1f + ((size_t)(0 * 1024 + tc * 512 + tid)) * 8,
                (char*)Bs[0] + (tc * 512 + tid) * 16);
    // (0b) stage Wg^T -> wgs (512 threads x 16B)
    {
        int r = tid >> 3, c0 = (tid & 7) * 8;
        *(short8*)(wgs + r * 72 + c0) = *(const short8*)(Wgt + r * 64 + c0);
    }

    // (1) gather (verbatim k_gcn inner loop; 8 rounds of 2 rows per wave)
    {
        int half = lane >> 5, l = lane & 31;
        for (int rr = 0; rr < 8; ++rr) {
            int lrow = w * 16 + rr * 2 + half;
            int row = m0 + lrow;
            float di = dinv[row];
            float2 st2 = *reinterpret_cast<const float2*>(state + (size_t)row * 64 + 2 * l);
            int s0 = offs[row], c = cnt[row];
            float x0 = 0.f, y0 = 0.f, x1 = 0.f, y1 = 0.f;
            float x2 = 0.f, y2 = 0.f, x3 = 0.f, y3 = 0.f;
            int e = 0;
            for (; e + 8 <= c; e += 8) {
                int sa = csr[s0 + e + 0];
                int sb = csr[s0 + e + 1];
                int sc = csr[s0 + e + 2];
                int sd = csr[s0 + e + 3];
                int se = csr[s0 + e + 4];
                int sf = csr[s0 + e + 5];
                int sg = csr[s0 + e + 6];
                int sh = csr[s0 + e + 7];
                uint32 va = ssb32[(size_t)sa * 32 + l];
                uint32 vb = ssb32[(size_t)sb * 32 + l];
                uint32 vc = ssb32[(size_t)sc * 32 + l];
                uint32 vd = ssb32[(size_t)sd * 32 + l];
                uint32 ve = ssb32[(size_t)se * 32 + l];
                uint32 vf = ssb32[(size_t)sf * 32 + l];
                uint32 vg = ssb32[(size_t)sg * 32 + l];
                uint32 vh = ssb32[(size_t)sh * 32 + l];
                x0 += bflo(va); y0 += bfhi(va);
                x1 += bflo(vb); y1 += bfhi(vb);
                x2 += bflo(vc); y2 += bfhi(vc);
                x3 += bflo(vd); y3 += bfhi(vd);
                x0 += bflo(ve); y0 += bfhi(ve);
                x1 += bflo(vf); y1 += bfhi(vf);
                x2 += bflo(vg); y2 += bfhi(vg);
                x3 += bflo(vh); y3 += bfhi(vh);
            }
            for (; e + 4 <= c; e += 4) {
                int sa = csr[s0 + e + 0];
                int sb = csr[s0 + e + 1];
                int sc = csr[s0 + e + 2];
                int sd = csr[s0 + e + 3];
                uint32 va = ssb32[(size_t)sa * 32 + l];
                uint32 vb = ssb32[(size_t)sb * 32 + l];
                uint32 vc = ssb32[(size_t)sc * 32 + l];
                uint32 vd = ssb32[(size_t)sd * 32 + l];
                x0 += bflo(va); y0 += bfhi(va);
                x1 += bflo(vb); y1 += bfhi(vb);
                x2 += bflo(vc); y2 += bfhi(vc);
                x3 += bflo(vd); y3 += bfhi(vd);
            }
            for (; e < c; ++e) {
                int sv2 = csr[s0 + e];
                uint32 v = ssb32[(size_t)sv2 * 32 + l];
                x0 += bflo(v); y0 += bfhi(v);
            }
            float ax = ((x0 + x1) + (x2 + x3)) * di + di * di * st2.x;
            float ay = ((y0 + y1) + (y2 + y3)) * di + di * di * st2.y;
            av[lrow * 36 + l] = pack2bf(ax, ay);
        }
    }
    __syncthreads();   // av + wgs ready; W1 tile-0 drained (vmcnt 0 at barrier)

    // (2) xW: x = relu(agg @ Wg + bg) + state ; swapped-operand MFMA so lane
    // holds x[row=s][j = jt*16 + g*4 + r]. K=64 in 2 steps.
    {
        f32x4 accx[4] = {};
        #pragma unroll
        for (int kk = 0; kk < 2; ++kk) {
            short8 bfa = *(const short8*)((const char*)av +
                          (((w * 16 + s) * 36 + kk * 16 + g * 4) << 2));
            #pragma unroll
            for (int jt = 0; jt < 4; ++jt) {
                short8 af = *(const short8*)(wgs + (jt * 16 + s) * 72 + kk * 32 + g * 8);
                accx[jt] = __builtin_amdgcn_mfma_f32_16x16x32_bf16(af, bfa, accx[jt], 0, 0, 0);
            }
        }
        #pragma unroll
        for (int jt = 0; jt < 4; ++jt) {
            int j0 = jt * 16 + g * 4;
            float4 bg4 = *(const float4*)(bg + j0);
            float4 st4 = *(const float4*)(state + (size_t)myrow * 64 + j0);
            float xv0 = fmaxf(accx[jt][0] + bg4.x, 0.f) + st4.x;
            float xv1 = fmaxf(accx[jt][1] + bg4.y, 0.f) + st4.y;
            float xv2 = fmaxf(accx[jt][2] + bg4.z, 0.f) + st4.z;
            float xv3 = fmaxf(accx[jt][3] + bg4.w, 0.f) + st4.w;
            uint32* dst = &xs[(w * 16 + s) * 36 + jt * 8 + g * 2];
            dst[0] = pack2bf(xv0, xv1);
            dst[1] = pack2bf(xv2, xv3);
        }
    }
    __syncthreads();   // xs ready

    // x fragments for MLP kt=0,1 from xs
    short8 xf0 = *(const short8*)((const char*)xs + (((w * 16 + s) * 36 + g * 4) << 2));
    short8 xf1 = *(const short8*)((const char*)xs + (((w * 16 + s) * 36 + 16 + g * 4) << 2));

    f32x4 acc1[16] = {};
    float4 pa0 = {0.f, 0.f, 0.f, 0.f}, pa1 = {0.f, 0.f, 0.f, 0.f};
    int cur = 0;

    // ---- MLP phase 1: H1 = relu(W1^T-mfma), K=192 (k=164 = bias-1 slot) ----
    #pragma unroll
    for (int kt = 0; kt < 6; ++kt) {
        int nxt = cur ^ 1;
        short8 bf;
        if (kt == 0) bf = xf0;
        else if (kt == 1) bf = xf1;
        else if (kt < 5) {
            ushort tm[8];
            tm[0] = f2bf(pa0.x); tm[1] = f2bf(pa0.y); tm[2] = f2bf(pa0.z); tm[3] = f2bf(pa0.w);
            tm[4] = f2bf(pa1.x); tm[5] = f2bf(pa1.y); tm[6] = f2bf(pa1.z); tm[7] = f2bf(pa1.w);
            bf = *(const short8*)tm;
        } else {
            ushort tm[8];
            if (g == 0) {
                tm[0] = f2bf(pa0.x); tm[1] = f2bf(pa0.y); tm[2] = f2bf(pa0.z); tm[3] = f2bf(pa0.w);
                tm[4] = (ushort)0x3F80; tm[5] = 0; tm[6] = 0; tm[7] = 0;
            } else {
                #pragma unroll
                for (int u = 0; u < 8; ++u) tm[u] = 0;
            }
            bf = *(const short8*)tm;
        }
        if (kt >= 1 && kt <= 3) {
            int c0 = (kt + 1) * 32 - 64 + g * 8;
            pa0 = *(const float4*)(abp + c0);
            pa1 = *(const float4*)(abp + c0 + 4);
        } else if (kt == 4) {
            if (g == 0) pa0 = *(const float4*)(abp + 96);
        }
        if (kt < 5) {
            #pragma unroll
            for (int tc = 0; tc < 2; ++tc)
                gload16(W1f + ((size_t)((kt + 1) * 1024 + tc * 512 + tid)) * 8,
                        (char*)Bs[nxt] + (tc * 512 + tid) * 16);
        } else {
            #pragma unroll
            for (int tc = 0; tc < 2; ++tc)
                gload16(W2f + ((size_t)(0 * 1024 + tc * 512 + tid)) * 8,
                        (char*)Bs[nxt] + (tc * 512 + tid) * 16);
        }
        #pragma unroll
        for (int jt = 0; jt < 16; ++jt) {
            short8 af = *(const short8*)((const char*)Bs[cur] + jt * 1024 + lane * 16);
            acc1[jt] = __builtin_amdgcn_mfma_f32_16x16x32_bf16(af, bf, acc1[jt], 0, 0, 0);
        }
        __syncthreads();
        cur = nxt;
    }

    // relu + pack H1 to bf16 pairs
    uint32 q0[16], q1[16];
    #pragma unroll
    for (int jt = 0; jt < 16; ++jt) {
        q0[jt] = pack2bf(fmaxf(acc1[jt][0], 0.f), fmaxf(acc1[jt][1], 0.f));
        q1[jt] = pack2bf(fmaxf(acc1[jt][2], 0.f), fmaxf(acc1[jt][3], 0.f));
    }

    // ---- MLP phase 2: h2 = relu(H1 @ W2^T + b2), K=256; A via shuffles ----
    f32x4 acc2[16] = {};
    int src0 = ((lane & 16) << 1) | s;
    int src1 = src0 + 16;
    bool hiSel = (lane & 32) != 0;
    #pragma unroll
    for (int kt = 0; kt < 8; ++kt) {
        int nxt = cur ^ 1;
        if (kt < 7) {
            #pragma unroll
            for (int tc = 0; tc < 2; ++tc)
                gload16(W2f + ((size_t)((kt + 1) * 1024 + tc * 512 + tid)) * 8,
                        (char*)Bs[nxt] + (tc * 512 + tid) * 16);
        }
        uint32 al0 = (uint32)__shfl((int)q0[2 * kt],     src0);
        uint32 ah0 = (uint32)__shfl((int)q0[2 * kt + 1], src0);
        uint32 bl0 = (uint32)__shfl((int)q1[2 * kt],     src0);
        uint32 bh0 = (uint32)__shfl((int)q1[2 * kt + 1], src0);
        uint32 al1 = (uint32)__shfl((int)q0[2 * kt],     src1);
        uint32 ah1 = (uint32)__shfl((int)q0[2 * kt + 1], src1);
        uint32 bl1 = (uint32)__shfl((int)q1[2 * kt],     src1);
        uint32 bh1 = (uint32)__shfl((int)q1[2 * kt + 1], src1);
        short8 af;
        uint32* afp = (uint32*)&af;
        afp[0] = hiSel ? ah0 : al0;
        afp[1] = hiSel ? bh0 : bl0;
        afp[2] = hiSel ? ah1 : al1;
        afp[3] = hiSel ? bh1 : bl1;
        #pragma unroll
        for (int nt = 0; nt < 16; ++nt) {
            short8 bf = *(const short8*)((const char*)Bs[cur] + nt * 1024 + lane * 16);
            acc2[nt] = __builtin_amdgcn_mfma_f32_16x16x32_bf16(af, bf, acc2[nt], 0, 0, 0);
        }
        __syncthreads();
        cur = nxt;
    }

    // ---- epilogue: relu+b2, xW3, row-sum, per-graph reduce ----
    float vsum[4] = {0.f, 0.f, 0.f, 0.f};
    #pragma unroll
    for (int nt = 0; nt < 16; ++nt) {
        float b2v = b2[nt * 16 + s];
        float w3v = W3[nt * 16 + s];
        #pragma unroll
        for (int r = 0; r < 4; ++r)
            vsum[r] += fmaxf(acc2[nt][r] + b2v, 0.f) * w3v;
    }
    float* red = (float*)Bs;
    #pragma unroll
    for (int r = 0; r < 4; ++r) {
        float v = vsum[r];
        v += __shfl_xor(v, 1);
        v += __shfl_xor(v, 2);
        v += __shfl_xor(v, 4);
        v += __shfl_xor(v, 8);
        if (s == 0) red[w * 16 + g * 4 + r] = v;
    }
    __syncthreads();
    if (tid < 128) {
        float sv = red[tid];
        int half64 = tid >> 6;
        int lt = tid & 63;
        int gbase = m0 + half64 * 64;
        int g0 = gbase / 100;
        int r0 = gbase - g0 * 100;
        int split = 100 - r0; if (split > 64) split = 64;
        float v0 = (lt < split) ? sv : 0.f;
        float vs = sv;
        #pragma unroll
        for (int d = 1; d < 64; d <<= 1) {
            v0 += __shfl_xor(v0, d);
            vs += __shfl_xor(vs, d);
        }
        if (lt == 0) {
            atomicAdd(&out[g0], v0);
            if (split < 64) atomicAdd(&out[g0 + 1], vs - v0);
        }
    }
}

__global__ void k_init_out(float* __restrict__ out, const float* __restrict__ b3) {
    int i = blockIdx.x * 256 + threadIdx.x;
    out[i] = b3[0];
}

// ---------------- launch ----------------

extern "C" void kernel_launch(void* const* d_in, const int* in_sizes, int n_in,
                              void* d_out, int out_size, void* d_ws, size_t ws_size,
                              hipStream_t stream) {
    const float* state  = (const float*)d_in[0];
    const int*   ei     = (const int*)d_in[1];
    const float* action = (const float*)d_in[2];
    const float* Wg     = (const float*)d_in[3];
    const float* bg     = (const float*)d_in[4];
    const float* W1     = (const float*)d_in[5];
    const float* b1     = (const float*)d_in[6];
    const float* W2     = (const float*)d_in[7];
    const float* b2     = (const float*)d_in[8];
    const float* W3     = (const float*)d_in[9];
    const float* b3     = (const float*)d_in[10];
    float* out = (float*)d_out;

    char* ws = (char*)d_ws;
    uint32* part  = (uint32*)(ws + 0);                 // 13,107,200
    uint32* ssb32 = (uint32*)(ws + 13107200);          // 26,214,400
    int*   csr    = (int*)  (ws + 65536000);           // 13,107,200
    int*   cnt    = (int*)  (ws + 78643200);           //    819,200
    int*   offs   = (int*)  (ws + 79462400);           //    819,200
    float* dinv   = (float*)(ws + 80281600);           //    819,200
    int*   bcnt   = (int*)  (ws + 81100800);           //      1,600
    int*   boffs  = (int*)  (ws + 81102400);           //      1,600
    int*   bcur   = (int*)  (ws + 81104000);           //      1,600
    ushort* W1f   = (ushort*)(ws + 81105600);          //     98,304
    ushort* W2f   = (ushort*)(ws + 81203904);          //    131,072
    ushort* Wgt   = (ushort*)(ws + 81334976);          //      8,192 -> end 81,343,168

    hipMemsetAsync(bcnt, 0, NBKT * sizeof(int), stream);
    k_init_out<<<NB / 256, 256, 0, stream>>>(out, b3);

    k_bhist<<<N_EDGES / 4096, 256, 0, stream>>>(ei, bcnt);
    k_bscan<<<1, 512, 0, stream>>>(bcnt, boffs, bcur);
    k_bscat<<<N_EDGES / 4096, 256, 0, stream>>>(ei, bcur, part);
    k_sortb<<<NBKT, 512, 0, stream>>>(part, boffs, bcnt, csr, cnt, offs, dinv,
                                      state, ssb32);
    k_packW<<<(49152 + 65536 + 4096 + 255) / 256, 256, 0, stream>>>(
        W1, W2, Wg, b1, W1f, W2f, Wgt);
    k_mlpf<<<N_NODES / 128, 512, 0, stream>>>(ssb32, state, csr, offs, cnt, dinv,
                                              Wgt, bg, action, W1f, W2f, b2, W3, out);
}

// Round 17
// 269.817 us; speedup vs baseline: 1.2110x; 1.2110x over previous
//
#include <hip/hip_runtime.h>
#include <hip/hip_bf16.h>
#include <cstdint>
#include <cstddef>

#define N_NODES 204800
#define N_EDGES 3276800
#define NB 2048
#define NR 100
#define NC 64
#define NH 256
#define KPAD 192          // 64 + 100 + bias(1) padded to 192 (6 x K32 steps)
#define NBKT 400          // buckets of 512 dst nodes

typedef __attribute__((ext_vector_type(8))) short short8;
typedef __attribute__((ext_vector_type(4))) float f32x4;
typedef unsigned int uint32;

__device__ __forceinline__ void gload16(const void* g, void* l) {
    __builtin_amdgcn_global_load_lds(
        (const __attribute__((address_space(1))) uint32_t*)(g),
        (__attribute__((address_space(3))) uint32_t*)(l), 16, 0, 0);
}

__device__ __forceinline__ ushort f2bf(float v) {
    __hip_bfloat16 h = __float2bfloat16(v);
    return *reinterpret_cast<ushort*>(&h);
}

__device__ __forceinline__ uint32 pack2bf(float a, float b) {
    return (uint32)f2bf(a) | ((uint32)f2bf(b) << 16);
}

__device__ __forceinline__ float bflo(uint32 v) { return __uint_as_float(v << 16); }
__device__ __forceinline__ float bfhi(uint32 v) { return __uint_as_float(v & 0xFFFF0000u); }

// ---------------- bucket histogram (4096 edges/block) ----------------

__global__ __launch_bounds__(256) void k_bhist(const int* __restrict__ ei,
                                               int* __restrict__ bcnt) {
    __shared__ int h[NBKT];
    int t = threadIdx.x;
    for (int i = t; i < NBKT; i += 256) h[i] = 0;
    __syncthreads();
    #pragma unroll 16
    for (int k = 0; k < 16; ++k) {
        int e = blockIdx.x * 4096 + k * 256 + t;
        atomicAdd(&h[ei[N_EDGES + e] >> 9], 1);
    }
    __syncthreads();
    for (int i = t; i < NBKT; i += 256)
        if (h[i]) atomicAdd(&bcnt[i], h[i]);
}

__global__ void k_bscan(const int* __restrict__ bcnt, int* __restrict__ boffs,
                        int* __restrict__ bcur) {
    __shared__ int tmp[512];
    int t = threadIdx.x;
    int v = (t < NBKT) ? bcnt[t] : 0;
    tmp[t] = v;
    __syncthreads();
    for (int off = 1; off < 512; off <<= 1) {
        int x = 0;
        if (t >= off) x = tmp[t - off];
        __syncthreads();
        tmp[t] += x;
        __syncthreads();
    }
    if (t < NBKT) {
        int o = tmp[t] - v;
        boffs[t] = o;
        bcur[t] = o;
    }
}

// radix partition v2: 4096 edges/block, count -> reserve -> re-read & write.
// Larger per-bucket chunks (~10 edges = 40B) cut scattered-write amplification.
__global__ __launch_bounds__(256) void k_bscat(const int* __restrict__ ei,
                                               int* __restrict__ bcur,
                                               uint32* __restrict__ part) {
    __shared__ int hist[NBKT];
    __shared__ int curb[NBKT];
    int tid = threadIdx.x;
    for (int i = tid; i < NBKT; i += 256) hist[i] = 0;
    __syncthreads();
    #pragma unroll 16
    for (int k = 0; k < 16; ++k) {
        int e = blockIdx.x * 4096 + k * 256 + tid;
        atomicAdd(&hist[ei[N_EDGES + e] >> 9], 1);
    }
    __syncthreads();
    for (int i = tid; i < NBKT; i += 256) {
        int c = hist[i];
        curb[i] = c ? atomicAdd(&bcur[i], c) : 0;
    }
    __syncthreads();
    #pragma unroll 16
    for (int k = 0; k < 16; ++k) {
        int e = blockIdx.x * 4096 + k * 256 + tid;   // re-read: L2-hot
        int s = ei[e];
        int d = ei[N_EDGES + e];
        int b = d >> 9;
        int p = atomicAdd(&curb[b], 1);
        part[p] = (uint32)s | ((uint32)(d & 511) << 18);
    }
}

// per-bucket counting sort -> CSR ; emits cnt/offs/dinv AND fused ssb
// (block b owns nodes b*512..+511; ssb[i][c] = bf16(dinv[i]*state[i][c]))
__global__ __launch_bounds__(512) void k_sortb(
    const uint32* __restrict__ part, const int* __restrict__ boffs,
    const int* __restrict__ bcnt, int* __restrict__ csr,
    int* __restrict__ cnt, int* __restrict__ offs, float* __restrict__ dinv,
    const float* __restrict__ state, uint32* __restrict__ ssb32) {
    __shared__ int h[512];
    __shared__ int cur[512];
    __shared__ float sdv[512];
    int b = blockIdx.x, t = threadIdx.x;
    h[t] = 0;
    __syncthreads();
    int base = boffs[b], n = bcnt[b];
    for (int i = t; i < n; i += 512)
        atomicAdd(&h[part[base + i] >> 18], 1);
    __syncthreads();
    int v = h[t];
    int node = b * 512 + t;
    cnt[node] = v;
    float dv = rsqrtf((float)(v + 1));          // +1 self loop
    dinv[node] = dv;
    sdv[t] = dv;
    __syncthreads();
    for (int off = 1; off < 512; off <<= 1) {
        int x = 0;
        if (t >= off) x = h[t - off];
        __syncthreads();
        h[t] += x;
        __syncthreads();
    }
    int excl = h[t] - v;
    offs[node] = base + excl;
    cur[t] = excl;
    __syncthreads();
    for (int i = t; i < n; i += 512) {
        uint32 ew = part[base + i];
        int dl = ew >> 18;
        int pos = atomicAdd(&cur[dl], 1);
        csr[base + pos] = (int)(ew & 0x3FFFF);
    }
    // fused ssb for this block's 512 nodes (coalesced float2 reads)
    __syncthreads();
    for (int i = t; i < 512 * 32; i += 512) {
        int nl = i >> 5, u = i & 31;
        float d = sdv[nl];
        size_t idx = (size_t)(b * 512 + nl) * 32 + u;
        float2 sv = reinterpret_cast<const float2*>(state)[idx];
        ssb32[idx] = pack2bf(sv.x * d, sv.y * d);
    }
}

// ---------------- GCN: dual-row gather (unroll 8) + MFMA xW + relu + residual ----------------
__global__ __launch_bounds__(256) void k_gcn(
    const uint32* __restrict__ ssb32, const float* __restrict__ state,
    const int* __restrict__ csr, const int* __restrict__ offs,
    const int* __restrict__ cnt, const float* __restrict__ dinv,
    const ushort* __restrict__ Wgt, const float* __restrict__ bg,
    ushort* __restrict__ xb16) {
    __shared__ uint32 av[32 * 36];     // [32 rows][36 dwords] (72-short pitch)
    __shared__ ushort wgs[64 * 72];    // Wg^T padded: [n][72]
    int tid = threadIdx.x;
    int w = tid >> 6, lane = tid & 63;
    int half = lane >> 5, l = lane & 31;
    int R0 = blockIdx.x * 32;

    // stage Wg^T (bf16, n-major) -> padded LDS
    {
        int r = tid >> 2, c0 = (tid & 3) * 16;
        short8 v0 = *(const short8*)(Wgt + r * 64 + c0);
        short8 v1 = *(const short8*)(Wgt + r * 64 + c0 + 8);
        *(short8*)(wgs + r * 72 + c0) = v0;
        *(short8*)(wgs + r * 72 + c0 + 8) = v1;
    }

    for (int rr = 0; rr < 4; ++rr) {
        int lrow = w * 8 + rr * 2 + half;
        int row = R0 + lrow;
        float di = dinv[row];
        float2 st2 = *reinterpret_cast<const float2*>(state + (size_t)row * 64 + 2 * l);
        int s0 = offs[row], c = cnt[row];
        float x0 = 0.f, y0 = 0.f, x1 = 0.f, y1 = 0.f;
        float x2 = 0.f, y2 = 0.f, x3 = 0.f, y3 = 0.f;
        int e = 0;
        for (; e + 8 <= c; e += 8) {
            int sa = csr[s0 + e + 0];
            int sb = csr[s0 + e + 1];
            int sc = csr[s0 + e + 2];
            int sd = csr[s0 + e + 3];
            int se = csr[s0 + e + 4];
            int sf = csr[s0 + e + 5];
            int sg = csr[s0 + e + 6];
            int sh = csr[s0 + e + 7];
            uint32 va = ssb32[(size_t)sa * 32 + l];
            uint32 vb = ssb32[(size_t)sb * 32 + l];
            uint32 vc = ssb32[(size_t)sc * 32 + l];
            uint32 vd = ssb32[(size_t)sd * 32 + l];
            uint32 ve = ssb32[(size_t)se * 32 + l];
            uint32 vf = ssb32[(size_t)sf * 32 + l];
            uint32 vg = ssb32[(size_t)sg * 32 + l];
            uint32 vh = ssb32[(size_t)sh * 32 + l];
            x0 += bflo(va); y0 += bfhi(va);
            x1 += bflo(vb); y1 += bfhi(vb);
            x2 += bflo(vc); y2 += bfhi(vc);
            x3 += bflo(vd); y3 += bfhi(vd);
            x0 += bflo(ve); y0 += bfhi(ve);
            x1 += bflo(vf); y1 += bfhi(vf);
            x2 += bflo(vg); y2 += bfhi(vg);
            x3 += bflo(vh); y3 += bfhi(vh);
        }
        for (; e + 4 <= c; e += 4) {
            int sa = csr[s0 + e + 0];
            int sb = csr[s0 + e + 1];
            int sc = csr[s0 + e + 2];
            int sd = csr[s0 + e + 3];
            uint32 va = ssb32[(size_t)sa * 32 + l];
            uint32 vb = ssb32[(size_t)sb * 32 + l];
            uint32 vc = ssb32[(size_t)sc * 32 + l];
            uint32 vd = ssb32[(size_t)sd * 32 + l];
            x0 += bflo(va); y0 += bfhi(va);
            x1 += bflo(vb); y1 += bfhi(vb);
            x2 += bflo(vc); y2 += bfhi(vc);
            x3 += bflo(vd); y3 += bfhi(vd);
        }
        for (; e < c; ++e) {
            int s = csr[s0 + e];
            uint32 v = ssb32[(size_t)s * 32 + l];
            x0 += bflo(v); y0 += bfhi(v);
        }
        float ax = ((x0 + x1) + (x2 + x3)) * di + di * di * st2.x;
        float ay = ((y0 + y1) + (y2 + y3)) * di + di * di * st2.y;
        av[lrow * 36 + l] = pack2bf(ax, ay);
    }
    __syncthreads();

    // MFMA: C = av(32x64) @ Wg(64x64); wave w owns cols w*16..+15
    int l15 = lane & 15, l4 = lane >> 4;
    const ushort* avs = (const ushort*)av;
    f32x4 acc[2] = {};
    #pragma unroll
    for (int kk = 0; kk < 2; ++kk) {
        short8 bf = *(const short8*)(wgs + (w * 16 + l15) * 72 + kk * 32 + l4 * 8);
        #pragma unroll
        for (int mt = 0; mt < 2; ++mt) {
            short8 af = *(const short8*)(avs + (mt * 16 + l15) * 72 + kk * 32 + l4 * 8);
            acc[mt] = __builtin_amdgcn_mfma_f32_16x16x32_bf16(af, bf, acc[mt], 0, 0, 0);
        }
    }
    int col = w * 16 + l15;
    float bgv = bg[col];
    #pragma unroll
    for (int mt = 0; mt < 2; ++mt)
        #pragma unroll
        for (int r = 0; r < 4; ++r) {
            int row = R0 + mt * 16 + l4 * 4 + r;
            float v = fmaxf(acc[mt][r] + bgv, 0.f) + state[(size_t)row * 64 + col];
            xb16[(size_t)row * 64 + col] = f2bf(v);
        }
}

// ---------------- pack weights: FRAGMENT-MAJOR ----------------
// chunk id = (kt*4+i)*256 + tid, tid = wp*64+l. Chunk short u:
//   k = kt*32 + (l>>4)*8 + u ;  j = i*64 + wp*16 + (l&15)
// W1f row k==164 carries b1 (bias folded into GEMM via constant-1 input).
__global__ void k_packW(const float* __restrict__ W1, const float* __restrict__ W2,
                        const float* __restrict__ Wg, const float* __restrict__ b1,
                        ushort* __restrict__ W1f, ushort* __restrict__ W2f,
                        ushort* __restrict__ Wgt) {
    int t = blockIdx.x * 256 + threadIdx.x;
    if (t < 6 * 4 * 256 * 8) {                      // W1f: 49152 shorts
        int u = t & 7, chunk = t >> 3;
        int tid = chunk & 255, ktI = chunk >> 8;
        int kt = ktI >> 2, i = ktI & 3;
        int l = tid & 63, wp = tid >> 6;
        int k = kt * 32 + (l >> 4) * 8 + u;
        int j = i * 64 + wp * 16 + (l & 15);
        ushort v = 0;
        if (k < NC + NR) v = f2bf(W1[(size_t)k * NH + j]);
        else if (k == NC + NR) v = f2bf(b1[j]);
        W1f[t] = v;
    } else if (t < 49152 + 8 * 4 * 256 * 8) {       // W2f: 65536 shorts
        int t2 = t - 49152;
        int u = t2 & 7, chunk = t2 >> 3;
        int tid = chunk & 255, ktI = chunk >> 8;
        int kt = ktI >> 2, i = ktI & 3;
        int l = tid & 63, wp = tid >> 6;
        int k = kt * 32 + (l >> 4) * 8 + u;
        int j = i * 64 + wp * 16 + (l & 15);
        W2f[t2] = f2bf(W2[(size_t)k * NH + j]);
    } else {
        int t3 = t - 49152 - 65536;
        if (t3 < 64 * 64) {
            int n = t3 >> 6, k = t3 & 63;
            Wgt[t3] = f2bf(Wg[(size_t)k * 64 + n]);
        }
    }
}

// ---------------- fused MLP v4b (keeper): 8 waves / 128 rows, register H1 ----------------
__global__ __launch_bounds__(512, 4) void k_mlpf(
    const ushort* __restrict__ xb16, const float* __restrict__ action,
    const ushort* __restrict__ W1f, const ushort* __restrict__ W2f,
    const float* __restrict__ b2, const float* __restrict__ W3,
    float* __restrict__ out) {
    __shared__ __align__(16) ushort Bs[2][256 * 32];   // 32 KB total
    int tid = threadIdx.x;
    int w = tid >> 6, lane = tid & 63;
    int s = lane & 15, g = lane >> 4;
    int m0 = blockIdx.x * 128;
    int myrow = m0 + w * 16 + s;
    int gb = myrow / 100, grr = myrow - gb * 100;
    const float* abp = action + (size_t)gb * 10000 + (size_t)grr * 100;

    // x fragments for kt=0,1 (registers; per-lane 16B loads, L2-resident)
    short8 xf0 = *(const short8*)(xb16 + (size_t)myrow * 64 + g * 8);
    short8 xf1 = *(const short8*)(xb16 + (size_t)myrow * 64 + 32 + g * 8);

    // prologue: stage W1 kt=0 (1024 chunks of 16B, 512 threads -> 2 each)
    #pragma unroll
    for (int tc = 0; tc < 2; ++tc)
        gload16(W1f + ((size_t)(0 * 1024 + tc * 512 + tid)) * 8,
                (char*)Bs[0] + (tc * 512 + tid) * 16);
    __syncthreads();

    f32x4 acc1[16] = {};
    float4 pa0 = {0.f, 0.f, 0.f, 0.f}, pa1 = {0.f, 0.f, 0.f, 0.f};
    int cur = 0;

    // ---- phase 1: H1 = relu(W1^T-mfma), K=192 (k=164 is the bias-1 slot) ----
    #pragma unroll
    for (int kt = 0; kt < 6; ++kt) {
        int nxt = cur ^ 1;
        // build bf (x operand) for this kt from registers
        short8 bf;
        if (kt == 0) bf = xf0;
        else if (kt == 1) bf = xf1;
        else if (kt < 5) {
            ushort tm[8];
            tm[0] = f2bf(pa0.x); tm[1] = f2bf(pa0.y); tm[2] = f2bf(pa0.z); tm[3] = f2bf(pa0.w);
            tm[4] = f2bf(pa1.x); tm[5] = f2bf(pa1.y); tm[6] = f2bf(pa1.z); tm[7] = f2bf(pa1.w);
            bf = *(const short8*)tm;
        } else {  // kt==5: cc = 96+g*8+u ; cc<100 action, cc==100 bias-1, else 0
            ushort tm[8];
            if (g == 0) {
                tm[0] = f2bf(pa0.x); tm[1] = f2bf(pa0.y); tm[2] = f2bf(pa0.z); tm[3] = f2bf(pa0.w);
                tm[4] = (ushort)0x3F80; tm[5] = 0; tm[6] = 0; tm[7] = 0;
            } else {
                #pragma unroll
                for (int u = 0; u < 8; ++u) tm[u] = 0;
            }
            bf = *(const short8*)tm;
        }
        // prefetch action regs for kt+1
        if (kt >= 1 && kt <= 3) {
            int c0 = (kt + 1) * 32 - 64 + g * 8;
            pa0 = *(const float4*)(abp + c0);
            pa1 = *(const float4*)(abp + c0 + 4);
        } else if (kt == 4) {
            if (g == 0) pa0 = *(const float4*)(abp + 96);
        }
        // stage next tile
        if (kt < 5) {
            #pragma unroll
            for (int tc = 0; tc < 2; ++tc)
                gload16(W1f + ((size_t)((kt + 1) * 1024 + tc * 512 + tid)) * 8,
                        (char*)Bs[nxt] + (tc * 512 + tid) * 16);
        } else {
            #pragma unroll
            for (int tc = 0; tc < 2; ++tc)
                gload16(W2f + ((size_t)(0 * 1024 + tc * 512 + tid)) * 8,
                        (char*)Bs[nxt] + (tc * 512 + tid) * 16);
        }
        // 16 MFMAs: af = W1 fragment for j-tile jt
        #pragma unroll
        for (int jt = 0; jt < 16; ++jt) {
            short8 af = *(const short8*)((const char*)Bs[cur] + jt * 1024 + lane * 16);
            acc1[jt] = __builtin_amdgcn_mfma_f32_16x16x32_bf16(af, bf, acc1[jt], 0, 0, 0);
        }
        __syncthreads();
        cur = nxt;
    }

    // relu + pack H1 to bf16 pairs: q0[jt]=(r0,r1), q1[jt]=(r2,r3)
    uint32 q0[16], q1[16];
    #pragma unroll
    for (int jt = 0; jt < 16; ++jt) {
        q0[jt] = pack2bf(fmaxf(acc1[jt][0], 0.f), fmaxf(acc1[jt][1], 0.f));
        q1[jt] = pack2bf(fmaxf(acc1[jt][2], 0.f), fmaxf(acc1[jt][3], 0.f));
    }

    // ---- phase 2: h2 = relu(H1 @ W2^T + b2), K=256; A from register shuffles ----
    f32x4 acc2[16] = {};
    int src0 = ((lane & 16) << 1) | s;   // lane 32*(g&1) + s
    int src1 = src0 + 16;
    bool hiSel = (lane & 32) != 0;       // g>=2 -> needs jt=2kt+1
    #pragma unroll
    for (int kt = 0; kt < 8; ++kt) {
        int nxt = cur ^ 1;
        if (kt < 7) {
            #pragma unroll
            for (int tc = 0; tc < 2; ++tc)
                gload16(W2f + ((size_t)((kt + 1) * 1024 + tc * 512 + tid)) * 8,
                        (char*)Bs[nxt] + (tc * 512 + tid) * 16);
        }
        // af assembly: k = 32kt + 8g + u ; source lanes 32*(g&1)+s (+16)
        uint32 al0 = (uint32)__shfl((int)q0[2 * kt],     src0);
        uint32 ah0 = (uint32)__shfl((int)q0[2 * kt + 1], src0);
        uint32 bl0 = (uint32)__shfl((int)q1[2 * kt],     src0);
        uint32 bh0 = (uint32)__shfl((int)q1[2 * kt + 1], src0);
        uint32 al1 = (uint32)__shfl((int)q0[2 * kt],     src1);
        uint32 ah1 = (uint32)__shfl((int)q0[2 * kt + 1], src1);
        uint32 bl1 = (uint32)__shfl((int)q1[2 * kt],     src1);
        uint32 bh1 = (uint32)__shfl((int)q1[2 * kt + 1], src1);
        short8 af;
        uint32* afp = (uint32*)&af;
        afp[0] = hiSel ? ah0 : al0;
        afp[1] = hiSel ? bh0 : bl0;
        afp[2] = hiSel ? ah1 : al1;
        afp[3] = hiSel ? bh1 : bl1;
        #pragma unroll
        for (int nt = 0; nt < 16; ++nt) {
            short8 bf = *(const short8*)((const char*)Bs[cur] + nt * 1024 + lane * 16);
            acc2[nt] = __builtin_amdgcn_mfma_f32_16x16x32_bf16(af, bf, acc2[nt], 0, 0, 0);
        }
        __syncthreads();
        cur = nxt;
    }

    // ---- epilogue: relu+b2, xW3, row-sum (over j lanes), per-graph reduce ----
    float vsum[4] = {0.f, 0.f, 0.f, 0.f};
    #pragma unroll
    for (int nt = 0; nt < 16; ++nt) {
        float b2v = b2[nt * 16 + s];
        float w3v = W3[nt * 16 + s];
        #pragma unroll
        for (int r = 0; r < 4; ++r)
            vsum[r] += fmaxf(acc2[nt][r] + b2v, 0.f) * w3v;
    }
    float* red = (float*)Bs;             // 128 f32 (Bs dead now)
    #pragma unroll
    for (int r = 0; r < 4; ++r) {
        float v = vsum[r];
        v += __shfl_xor(v, 1);
        v += __shfl_xor(v, 2);
        v += __shfl_xor(v, 4);
        v += __shfl_xor(v, 8);
        if (s == 0) red[w * 16 + g * 4 + r] = v;
    }
    __syncthreads();
    if (tid < 128) {                     // waves 0,1: each reduces 64 rows (<=2 graphs)
        float sv = red[tid];
        int half64 = tid >> 6;
        int lt = tid & 63;
        int gbase = m0 + half64 * 64;
        int g0 = gbase / 100;
        int r0 = gbase - g0 * 100;
        int split = 100 - r0; if (split > 64) split = 64;
        float v0 = (lt < split) ? sv : 0.f;
        float vs = sv;
        #pragma unroll
        for (int d = 1; d < 64; d <<= 1) {
            v0 += __shfl_xor(v0, d);
            vs += __shfl_xor(vs, d);
        }
        if (lt == 0) {
            atomicAdd(&out[g0], v0);
            if (split < 64) atomicAdd(&out[g0 + 1], vs - v0);
        }
    }
}

__global__ void k_init_out(float* __restrict__ out, const float* __restrict__ b3) {
    int i = blockIdx.x * 256 + threadIdx.x;
    out[i] = b3[0];
}

// ---------------- launch ----------------

extern "C" void kernel_launch(void* const* d_in, const int* in_sizes, int n_in,
                              void* d_out, int out_size, void* d_ws, size_t ws_size,
                              hipStream_t stream) {
    const float* state  = (const float*)d_in[0];
    const int*   ei     = (const int*)d_in[1];
    const float* action = (const float*)d_in[2];
    const float* Wg     = (const float*)d_in[3];
    const float* bg     = (const float*)d_in[4];
    const float* W1     = (const float*)d_in[5];
    const float* b1     = (const float*)d_in[6];
    const float* W2     = (const float*)d_in[7];
    const float* b2     = (const float*)d_in[8];
    const float* W3     = (const float*)d_in[9];
    const float* b3     = (const float*)d_in[10];
    float* out = (float*)d_out;

    char* ws = (char*)d_ws;
    uint32* part  = (uint32*)(ws + 0);                 // 13,107,200
    uint32* ssb32 = (uint32*)(ws + 13107200);          // 26,214,400
    ushort* xb16  = (ushort*)(ws + 39321600);          // 26,214,400
    int*   csr    = (int*)  (ws + 65536000);           // 13,107,200
    int*   cnt    = (int*)  (ws + 78643200);           //    819,200
    int*   offs   = (int*)  (ws + 79462400);           //    819,200
    float* dinv   = (float*)(ws + 80281600);           //    819,200
    int*   bcnt   = (int*)  (ws + 81100800);           //      1,600
    int*   boffs  = (int*)  (ws + 81102400);           //      1,600
    int*   bcur   = (int*)  (ws + 81104000);           //      1,600
    ushort* W1f   = (ushort*)(ws + 81105600);          //     98,304
    ushort* W2f   = (ushort*)(ws + 81203904);          //    131,072
    ushort* Wgt   = (ushort*)(ws + 81334976);          //      8,192 -> end 81,343,168

    hipMemsetAsync(bcnt, 0, NBKT * sizeof(int), stream);
    k_init_out<<<NB / 256, 256, 0, stream>>>(out, b3);

    k_bhist<<<N_EDGES / 4096, 256, 0, stream>>>(ei, bcnt);
    k_bscan<<<1, 512, 0, stream>>>(bcnt, boffs, bcur);
    k_bscat<<<N_EDGES / 4096, 256, 0, stream>>>(ei, bcur, part);
    k_sortb<<<NBKT, 512, 0, stream>>>(part, boffs, bcnt, csr, cnt, offs, dinv,
                                      state, ssb32);
    k_packW<<<(49152 + 65536 + 4096 + 255) / 256, 256, 0, stream>>>(
        W1, W2, Wg, b1, W1f, W2f, Wgt);
    k_gcn<<<N_NODES / 32, 256, 0, stream>>>(ssb32, state, csr, offs, cnt, dinv,
                                            Wgt, bg, xb16);
    k_mlpf<<<N_NODES / 128, 512, 0, stream>>>(xb16, action, W1f, W2f, b2, W3, out);
}